// Round 11
// baseline (38.419 us; speedup 1.0000x reference)
//
#include <hip/hip_runtime.h>
#include <math.h>

#define BB 4096
#define DD 1024
#define KK 5
#define PP 1323
#define PTS_PER_THREAD 7    // 1323 = 189 * 7
#define GYB 189

// (2*pi)^(-3/2)
#define INV_2PI_POW15 0.06349363593424097f

// ---- fused head config ----
#define GR   16       // rows per block -> 256 blocks (1 per CU)
#define NWV  16       // waves per block
#define RST  13       // s_red inner stride (12 + 1)
#define CSTR 49       // s_c inner stride
#define NG   13       // param groups of 4 (52 slots, 50 used)
#define WPKN 49152    // packed weight elements (32 chunks x 3 nt x 64 lanes x 8)

typedef short  bf16x8 __attribute__((ext_vector_type(8)));
typedef float  f32x4  __attribute__((ext_vector_type(4)));

__device__ __forceinline__ short f2bf(float f) {
    union { float f; unsigned u; } x; x.f = f;
    const unsigned r = x.u + 0x7fffu + ((x.u >> 16) & 1u);  // RNE
    return (short)(r >> 16);
}
__device__ __forceinline__ float softplus_f(float x) {
    return (x > 20.f) ? x : log1pf(expf(x));
}

__device__ __forceinline__ int wpk_index(int k, int j) {
    // Wpk[chunk][nt][lane][8]: k = chunk*32 + (lane>>4)*8 + ee, j = nt*16 + (lane&15)
    const int chunk = k >> 5;
    const int kin   = k & 31;
    const int lane  = ((kin >> 3) << 4) | (j & 15);
    const int nt    = j >> 4;
    const int ee    = k & 7;
    return ((chunk * 3 + nt) * 64 + lane) * 8 + ee;
}

// ---------------------------------------------------------------------------
// Kernel 1: fully-fused head (pack + GEMM + tail). 256 blocks x 1024 thr.
// Phase 0: cooperative weight conversion f32 -> bf16 fragment order in LDS
//          (coalesced source reads, 48 elems/thread, L3-cached across blocks).
// Phase 1: MFMA, wave w = k-slice [64w, 64w+64): A direct from global rep,
//          B from LDS s_wpk (consecutive-lane ds_read_b128, conflict-free).
// Phase 2: 16->8 tree reduce in LDS, cooperative C assembly.
// Phase 3: 80-thread (b,k) tail -> par4 (packed SoA) + s_L.
// Phase 4: coalesced Lout write (720 contiguous floats/block).
// ---------------------------------------------------------------------------
__global__ __launch_bounds__(1024, 4) void head_fused_kernel(
    const float* __restrict__ rep,
    const float* __restrict__ Wmix,
    const float* __restrict__ Wmean,
    const float* __restrict__ Wscale,
    const float* __restrict__ bmix,
    const float* __restrict__ bmean,
    const float* __restrict__ bscale,
    float* __restrict__ Lout,
    float* __restrict__ par4)
{
    __shared__ short s_wpk[WPKN];           // 96 KB
    __shared__ float s_red[8][64][RST];     // 26.6 KB
    __shared__ float s_c[GR][CSTR];         // 3.1 KB
    __shared__ float s_L[GR][KK][6];        // 1.9 KB

    const int t  = threadIdx.x;
    const int w  = t >> 6;          // wave 0..15
    const int l  = t & 63;
    const int lm = l & 15;
    const int lk = (l >> 4) * 8;
    const int b0 = blockIdx.x * GR;

    // ---- phase 0: pack weights into LDS (coalesced reads, 48/thread) ----
#pragma unroll
    for (int i = 0; i < WPKN / 1024; ++i) {
        const int e = i * 1024 + t;
        int k, j; float v;
        if (e < 5120) {                       // Wmix: [1024][5]
            k = e / 5;  j = e - k * 5;
            v = Wmix[e];
        } else if (e < 17408) {               // Wmean: [1024][12]
            const int idx = e - 5120;
            k = idx / 12; j = 5 + (idx - k * 12);
            v = Wmean[idx];
        } else if (e < 48128) {               // Wscale: [1024][30]
            const int idx = e - 17408;
            k = idx / 30; j = 17 + (idx - k * 30);
            v = Wscale[idx];
        } else {                              // zero-fill j = 47
            k = e - 48128; j = 47; v = 0.f;
        }
        s_wpk[wpk_index(k, j)] = f2bf(v);
    }
    __syncthreads();

    // ---- phase 1: MFMA over this wave's 64-k slice ----
    f32x4 acc[3] = {f32x4{0,0,0,0}, f32x4{0,0,0,0}, f32x4{0,0,0,0}};

#pragma unroll
    for (int kt = 0; kt < 2; ++kt) {
        const int chunk = w * 2 + kt;        // global 32-k chunk 0..31
        const int kof   = chunk * 32 + lk;

        const float* arow = rep + (size_t)(b0 + lm) * DD + kof;
        const f32x4 a0 = *(const f32x4*)(arow);
        const f32x4 a1 = *(const f32x4*)(arow + 4);

        bf16x8 ah;
#pragma unroll
        for (int u = 0; u < 4; ++u) {
            ah[u]     = f2bf(a0[u]);
            ah[u + 4] = f2bf(a1[u]);
        }

#pragma unroll
        for (int nt = 0; nt < 3; ++nt) {
            const bf16x8 bh = *(const bf16x8*)(&s_wpk[(((size_t)chunk * 3 + nt) * 64 + l) * 8]);
            acc[nt] = __builtin_amdgcn_mfma_f32_16x16x32_bf16(ah, bh, acc[nt], 0, 0, 0);
        }
    }

    // ---- phase 2: 16 -> 8 tree reduce via LDS ----
    if (w >= 8) {
#pragma unroll
        for (int nt = 0; nt < 3; ++nt)
#pragma unroll
            for (int r = 0; r < 4; ++r)
                s_red[w - 8][l][nt * 4 + r] = acc[nt][r];
    }
    __syncthreads();
    if (w < 8) {
#pragma unroll
        for (int nt = 0; nt < 3; ++nt)
#pragma unroll
            for (int r = 0; r < 4; ++r) {
                acc[nt][r] += s_red[w][l][nt * 4 + r];
                s_red[w][l][nt * 4 + r] = acc[nt][r];
            }
    }
    __syncthreads();

    // cooperative sum into s_c[b_loc][j]; C layout [m89]:
    // col(=j) = lane&15, row(=b_loc) = (lane>>4)*4 + reg
    if (t < GR * 47) {
        const int b_loc = t & 15;
        const int j     = t >> 4;
        const int lane  = ((b_loc >> 2) << 4) | (j & 15);
        const int reg   = ((j >> 4) << 2) | (b_loc & 3);
        float s = 0.f;
#pragma unroll
        for (int q = 0; q < 8; ++q) s += s_red[q][lane][reg];
        s_c[b_loc][j] = s;
    }
    __syncthreads();

    // ---- phase 3: tail, 80 threads = 16 b x 5 k ----
    if (t < GR * KK) {
        const int k     = t >> 4;
        const int b_loc = t & 15;
        const int b     = b0 + b_loc;

        float logits[KK];
#pragma unroll
        for (int kk = 0; kk < KK; ++kk) logits[kk] = s_c[b_loc][kk] + bmix[kk];

        float m[3];
#pragma unroll
        for (int c = 0; c < 3; ++c)
            m[c] = (k > 0) ? (s_c[b_loc][5 + (k - 1) * 3 + c] + bmean[(k - 1) * 3 + c]) : 0.f;

        float sc[6];
#pragma unroll
        for (int c = 0; c < 6; ++c)
            sc[c] = s_c[b_loc][17 + k * 6 + c] + bscale[k * 6 + c];

        float mx = logits[0];
#pragma unroll
        for (int kk = 1; kk < KK; ++kk) mx = fmaxf(mx, logits[kk]);
        float den = 0.f;
#pragma unroll
        for (int kk = 0; kk < KK; ++kk) den += expf(logits[kk] - mx);
        const float wgt = expf(logits[k] - mx) / den;

        const float L00 = softplus_f(sc[0]);
        const float L10 = sc[1];
        const float L11 = softplus_f(sc[2]);
        const float L20 = sc[3];
        const float L21 = sc[4];
        const float L22 = softplus_f(sc[5]);

        const float r00 = 1.f / L00;
        const float r11 = 1.f / L11;
        const float r22 = 1.f / L22;
        const float a   = wgt * r00 * r11 * r22 * INV_2PI_POW15;

        s_L[b_loc][k][0] = L00;
        s_L[b_loc][k][1] = L10;
        s_L[b_loc][k][2] = L11;
        s_L[b_loc][k][3] = L20;
        s_L[b_loc][k][4] = L21;
        s_L[b_loc][k][5] = L22;

        // packed param store: q = k*10 + i -> par4[(q>>2)*BB + b][q&3]
        float pv[10] = { m[0], m[1], m[2], r00, L10, r11, L20, L21, r22, a };
#pragma unroll
        for (int i = 0; i < 10; ++i) {
            const int q = k * 10 + i;
            par4[(((size_t)(q >> 2)) * BB + b) * 4 + (q & 3)] = pv[i];
        }
    }
    __syncthreads();

    // ---- phase 4: coalesced Lout write (720 contiguous floats) ----
    if (t < GR * KK * 9) {
        const int b_loc = t / 45;
        const int rem   = t - b_loc * 45;
        const int k     = rem / 9;
        const int e9    = rem - k * 9;
        const int rr    = e9 / 3;
        const int cc    = e9 - rr * 3;
        const float v = (cc > rr) ? 0.f : s_L[b_loc][k][(rr * (rr + 1)) / 2 + cc];
        Lout[(size_t)b0 * 45 + t] = v;
    }
}

// ---------------------------------------------------------------------------
// Kernel 2: per-(p,b) mixture density (memory-bound). Non-temporal streaming
// for dxyz/out (never reused) to keep L2 for par4.
// ---------------------------------------------------------------------------
__global__ __launch_bounds__(256) void eval_kernel(
    const float* __restrict__ dxyz,
    const float* __restrict__ par4,
    float* __restrict__ out)
{
    const int b = blockIdx.x * 256 + threadIdx.x;

    float pr[NG * 4];
#pragma unroll
    for (int g = 0; g < NG; ++g) {
        const f32x4 v = *(const f32x4*)(par4 + ((size_t)g * BB + b) * 4);
        pr[g * 4 + 0] = v[0];
        pr[g * 4 + 1] = v[1];
        pr[g * 4 + 2] = v[2];
        pr[g * 4 + 3] = v[3];
    }

    const int p0 = blockIdx.y * PTS_PER_THREAD;
#pragma unroll
    for (int i = 0; i < PTS_PER_THREAD; ++i) {
        const int p = p0 + i;
        const size_t idx = (size_t)p * BB + b;
        const float* xv = dxyz + idx * 3;
        const float x0 = __builtin_nontemporal_load(xv);
        const float x1 = __builtin_nontemporal_load(xv + 1);
        const float x2 = __builtin_nontemporal_load(xv + 2);

        float res = 0.f;
#pragma unroll
        for (int k = 0; k < KK; ++k) {
            const float d0 = x0 - pr[k * 10 + 0];
            const float d1 = x1 - pr[k * 10 + 1];
            const float d2 = x2 - pr[k * 10 + 2];
            const float z0 = d0 * pr[k * 10 + 3];
            const float z1 = fmaf(-pr[k * 10 + 4], z0, d1) * pr[k * 10 + 5];
            const float z2 = fmaf(-pr[k * 10 + 7], z1, fmaf(-pr[k * 10 + 6], z0, d2)) * pr[k * 10 + 8];
            const float q  = fmaf(z2, z2, fmaf(z1, z1, z0 * z0));
            res = fmaf(pr[k * 10 + 9], __expf(-0.5f * q), res);
        }
        __builtin_nontemporal_store(res, &out[idx]);
    }
}

extern "C" void kernel_launch(void* const* d_in, const int* in_sizes, int n_in,
                              void* d_out, int out_size, void* d_ws, size_t ws_size,
                              hipStream_t stream) {
    const float* rep    = (const float*)d_in[0];
    const float* dxyz   = (const float*)d_in[1];
    const float* Wmix   = (const float*)d_in[2];
    const float* bmix   = (const float*)d_in[3];
    const float* Wmean  = (const float*)d_in[4];
    const float* bmean  = (const float*)d_in[5];
    const float* Wscale = (const float*)d_in[6];
    const float* bscale = (const float*)d_in[7];

    float* out  = (float*)d_out;
    float* Lout = out + (size_t)BB * PP;          // second tuple output

    float* par4 = (float*)d_ws;                   // NG*BB*4 f32 (852 KB)

    head_fused_kernel<<<BB / GR, 1024, 0, stream>>>(rep, Wmix, Wmean, Wscale,
                                                    bmix, bmean, bscale, Lout, par4);

    eval_kernel<<<dim3(BB / 256, GYB), 256, 0, stream>>>(dxyz, par4, out);
}